// Round 12
// baseline (467.914 us; speedup 1.0000x reference)
//
#include <hip/hip_runtime.h>
#include <cstdint>
#include <cstddef>

#define NF 128
#define NH 64

typedef unsigned int uint32;
typedef short bf16x8 __attribute__((ext_vector_type(8)));
typedef float f32x4 __attribute__((ext_vector_type(4)));

// bf16 helpers (RNE pack, cheap unpack)
__device__ inline unsigned short f2bf(float f) {
  unsigned int u = __float_as_uint(f);
  return (unsigned short)((u + 0x7FFF + ((u >> 16) & 1)) >> 16);
}
__device__ inline float bf2f_lo(uint32 u) { return __uint_as_float(u << 16); }
__device__ inline float bf2f_hi(uint32 u) { return __uint_as_float(u & 0xFFFF0000u); }

// ---------------- fused gemm1 (MFMA) + count ----------------

// Blocks [0,G1): H = X @ W1 (f32 in, bf16-packed out) via mfma_f32_16x16x32_bf16.
// Blocks [G1,..): dst-windowed degree count, P=4 windows (pass = local&3).
__global__ __launch_bounds__(256) void gemm1_count_kernel(
    const float* __restrict__ X, const float* __restrict__ W,
    uint32* __restrict__ Hb, int N,
    const int* __restrict__ ei, int E, int* __restrict__ cnt, int RW, int G1) {
  if ((int)blockIdx.x >= G1) {
    int b = blockIdx.x - G1;
    int pass = b & 3;
    int i = (b >> 2) * 256 + threadIdx.x;
    if (i * 4 >= E) return;
    int4 d = ((const int4*)(ei + E))[i];
    int lo = pass * RW, hi = lo + RW;
    if (d.x >= lo && d.x < hi) atomicAdd(&cnt[d.x], 1);
    if (d.y >= lo && d.y < hi) atomicAdd(&cnt[d.y], 1);
    if (d.z >= lo && d.z < hi) atomicAdd(&cnt[d.z], 1);
    if (d.w >= lo && d.w < hi) atomicAdd(&cnt[d.w], 1);
    return;
  }

  // gemm1 (MFMA): wave = 16 nodes
  const int lane = threadIdx.x & 63;
  const int wv = threadIdx.x >> 6;
  const int m = lane & 15;
  const int g = lane >> 4;
  const int base = blockIdx.x * 64 + wv * 16;
  int row = base + m;
  int rowc = row < N ? row : N - 1;
  const float* xp = X + (size_t)rowc * 128 + g * 8;

  f32x4 acc[4];
#pragma unroll
  for (int nt = 0; nt < 4; ++nt) acc[nt] = (f32x4){0.f, 0.f, 0.f, 0.f};

#pragma unroll
  for (int kk = 0; kk < 4; ++kk) {
    float4 alo = *(const float4*)(xp + kk * 32);
    float4 ahi = *(const float4*)(xp + kk * 32 + 4);
    bf16x8 a;
    a[0] = (short)f2bf(alo.x); a[1] = (short)f2bf(alo.y);
    a[2] = (short)f2bf(alo.z); a[3] = (short)f2bf(alo.w);
    a[4] = (short)f2bf(ahi.x); a[5] = (short)f2bf(ahi.y);
    a[6] = (short)f2bf(ahi.z); a[7] = (short)f2bf(ahi.w);
    const float* wp = W + (size_t)(kk * 32 + g * 8) * 64 + m;
#pragma unroll
    for (int nt = 0; nt < 4; ++nt) {
      bf16x8 b;
#pragma unroll
      for (int i = 0; i < 8; ++i)
        b[i] = (short)f2bf(wp[(size_t)i * 64 + nt * 16]);
      acc[nt] = __builtin_amdgcn_mfma_f32_16x16x32_bf16(a, b, acc[nt], 0, 0, 0);
    }
  }
  unsigned short* Hs = (unsigned short*)Hb;
#pragma unroll
  for (int j = 0; j < 4; ++j) {
    int n = base + g * 4 + j;
    if (n < N) {
#pragma unroll
      for (int nt = 0; nt < 4; ++nt)
        Hs[(size_t)n * 64 + nt * 16 + m] = f2bf(acc[nt][j]);
    }
  }
}

// per-1024-element block sums
__global__ __launch_bounds__(256) void partial_kernel(const int* __restrict__ cnt, int N,
                                                      int* __restrict__ part) {
  __shared__ int sd[256];
  int t = threadIdx.x;
  int idx = blockIdx.x * 1024 + t * 4;
  int s = 0;
#pragma unroll
  for (int j = 0; j < 4; ++j)
    if (idx + j < N) s += cnt[idx + j];
  sd[t] = s;
  __syncthreads();
  for (int off = 128; off > 0; off >>= 1) {
    if (t < off) sd[t] += sd[t + off];
    __syncthreads();
  }
  if (t == 0) part[blockIdx.x] = sd[0];
}

// exclusive-scan the block partials (NB <= 128), write total to rowptr[N]
__global__ __launch_bounds__(128) void scanp_kernel(int* __restrict__ part, int NB,
                                                    int* __restrict__ rowptrN) {
  __shared__ int s[128];
  int t = threadIdx.x;
  int v = (t < NB) ? part[t] : 0;
  s[t] = v;
  __syncthreads();
  for (int off = 1; off < 128; off <<= 1) {
    int add = (t >= off) ? s[t - off] : 0;
    __syncthreads();
    s[t] += add;
    __syncthreads();
  }
  if (t < NB) part[t] = s[t] - v;  // exclusive
  if (t == 0) rowptrN[0] = s[127];
}

// rowptr (exclusive scan of cnt) + cnt2 (running cursor copy) + dinv
__global__ __launch_bounds__(256) void rowptr_kernel(const int* __restrict__ cnt,
                                                     const int* __restrict__ part,
                                                     int* __restrict__ rowptr,
                                                     int* __restrict__ cnt2,
                                                     float* __restrict__ dinv, int N) {
  __shared__ int s[256];
  int t = threadIdx.x;
  int idx = blockIdx.x * 1024 + t * 4;
  int c[4];
  int ts = 0;
#pragma unroll
  for (int j = 0; j < 4; ++j) {
    c[j] = (idx + j < N) ? cnt[idx + j] : 0;
    ts += c[j];
  }
  s[t] = ts;
  __syncthreads();
  for (int off = 1; off < 256; off <<= 1) {
    int add = (t >= off) ? s[t - off] : 0;
    __syncthreads();
    s[t] += add;
    __syncthreads();
  }
  int run = s[t] - ts + part[blockIdx.x];
#pragma unroll
  for (int j = 0; j < 4; ++j) {
    if (idx + j < N) {
      rowptr[idx + j] = run;
      cnt2[idx + j] = run;
      dinv[idx + j] = rsqrtf((float)(c[j] + 1));
    }
    run += c[j];
  }
}

// dst-windowed CSR scatter (src, weight), P=4 windows
__global__ __launch_bounds__(256) void fill_kernel(const int* __restrict__ ei, int E,
                                                   int* __restrict__ cnt2,
                                                   const float* __restrict__ dinv,
                                                   int2* __restrict__ col2, int RW) {
  int pass = blockIdx.x & 3;
  int i = (blockIdx.x >> 2) * 256 + threadIdx.x;
  if (i * 4 >= E) return;
  int4 sv = ((const int4*)ei)[i];
  int4 dv = ((const int4*)(ei + E))[i];
  int lo = pass * RW, hi = lo + RW;
  int ss[4] = {sv.x, sv.y, sv.z, sv.w};
  int dd[4] = {dv.x, dv.y, dv.z, dv.w};
#pragma unroll
  for (int j = 0; j < 4; ++j) {
    int d = dd[j];
    if (d < lo || d >= hi) continue;
    int s = ss[j];
    float w = dinv[s] * dinv[d];
    int pos = atomicAdd(&cnt2[d], 1);
    col2[pos] = make_int2(s, __float_as_int(w));
  }
}

// ---------------- prop kernel (R6 winner, layers 1 & 3) ----------------

template <int FINAL>
__global__ __launch_bounds__(256) void prop_fused_kernel(
    const uint32* __restrict__ H32, const int* __restrict__ rowptr,
    const int2* __restrict__ col2, const float* __restrict__ dinv,
    const float* __restrict__ bias, const float* __restrict__ Wn,
    const float* __restrict__ blin, void* __restrict__ outv, int N) {
  __shared__ float Ws[FINAL ? 4 : 64 * 64];
  __shared__ float rbuf[FINAL ? 1 : 4][64];
  const int lane = threadIdx.x & 63;
  const int widx = threadIdx.x >> 6;
  const int fl = lane & 31;
  const int half = lane >> 5;

  if (!FINAL) {
    const float4* Wg = (const float4*)Wn;
    float4* Wl = (float4*)Ws;
    for (int i = threadIdx.x; i < 1024; i += 256) Wl[i] = Wg[i];
    __syncthreads();
  }

  int n = blockIdx.x * 4 + widx;
  n = __builtin_amdgcn_readfirstlane(n);
  if (n >= N) return;

  int e0 = rowptr[n];
  int e1 = rowptr[n + 1];
  float di = dinv[n];
  const int2* ec = col2 + e0;
  const int m = e1 - e0;

  float acc0 = 0.f, acc1 = 0.f;
  if (half == 0) {
    uint32 u = H32[(size_t)n * 32 + fl];
    float w = di * di;
    acc0 = bf2f_lo(u) * w;
    acc1 = bf2f_hi(u) * w;
  }

  const int npair = m >> 1;
  const int nfull = npair >> 3;
  for (int b = 0; b < nfull; ++b) {
    int s[8];
    float wv[8];
#pragma unroll
    for (int j = 0; j < 8; ++j) {
      int2 c = ec[2 * (b * 8 + j) + half];
      s[j] = c.x;
      wv[j] = __int_as_float(c.y);
    }
    uint32 u[8];
#pragma unroll
    for (int j = 0; j < 8; ++j) u[j] = H32[(size_t)s[j] * 32 + fl];
#pragma unroll
    for (int j = 0; j < 8; ++j) {
      acc0 = fmaf(wv[j], bf2f_lo(u[j]), acc0);
      acc1 = fmaf(wv[j], bf2f_hi(u[j]), acc1);
    }
  }
  for (int t = nfull * 8; t < npair; ++t) {
    int2 c = ec[2 * t + half];
    uint32 u = H32[(size_t)c.x * 32 + fl];
    float w = __int_as_float(c.y);
    acc0 = fmaf(w, bf2f_lo(u), acc0);
    acc1 = fmaf(w, bf2f_hi(u), acc1);
  }
  if ((m & 1) && half == 0) {
    int2 c = ec[m - 1];
    uint32 u = H32[(size_t)c.x * 32 + fl];
    float w = __int_as_float(c.y);
    acc0 = fmaf(w, bf2f_lo(u), acc0);
    acc1 = fmaf(w, bf2f_hi(u), acc1);
  }
  acc0 += __shfl_xor(acc0, 32, 64);
  acc1 += __shfl_xor(acc1, 32, 64);

  float2 bv = ((const float2*)bias)[fl];
  float r0 = acc0 + bv.x;
  float r1 = acc1 + bv.y;
  r0 = r0 > 0.f ? r0 : 0.f;
  r1 = r1 > 0.f ? r1 : 0.f;

  if (FINAL) {
    float t0 = 0.f, t1 = 0.f;
    if (half == 0) {
      t0 = r0 * Wn[4 * fl + 0] + r1 * Wn[4 * fl + 2];
      t1 = r0 * Wn[4 * fl + 1] + r1 * Wn[4 * fl + 3];
    }
#pragma unroll
    for (int off = 32; off > 0; off >>= 1) {
      t0 += __shfl_xor(t0, off, 64);
      t1 += __shfl_xor(t1, off, 64);
    }
    if (lane == 0) {
      float* out = (float*)outv;
      float l0 = t0 + blin[0];
      float l1 = t1 + blin[1];
      float mx = fmaxf(l0, l1);
      float lz = mx + logf(expf(l0 - mx) + expf(l1 - mx));
      out[(size_t)n * 2 + 0] = l0 - lz;
      out[(size_t)n * 2 + 1] = l1 - lz;
    }
  } else {
    if (half == 0) *(float2*)(&rbuf[widx][2 * fl]) = make_float2(r0, r1);
    __builtin_amdgcn_wave_barrier();
    float o = 0.f;
#pragma unroll
    for (int q = 0; q < 16; ++q) {
      float4 rv = *(const float4*)(&rbuf[widx][4 * q]);
      o = fmaf(rv.x, Ws[(4 * q + 0) * 64 + lane], o);
      o = fmaf(rv.y, Ws[(4 * q + 1) * 64 + lane], o);
      o = fmaf(rv.z, Ws[(4 * q + 2) * 64 + lane], o);
      o = fmaf(rv.w, Ws[(4 * q + 3) * 64 + lane], o);
    }
    ((unsigned short*)outv)[(size_t)n * 64 + lane] = f2bf(o);
  }
}

// ---------------- layer-2 A/B: half-row sliced aggregation ----------------

// Aggregate one 64B feature half-slice per grid-half (slice working set 6.4MB
// -> ~60% L2 residency vs 31% full-row). Wave = node; 4 edges/instruction
// (16 lanes x u32). Writes relu(agg+bias) bf16 half-rows to Rout.
__global__ __launch_bounds__(256) void agg_half_kernel(
    const uint32* __restrict__ H32, const int* __restrict__ rowptr,
    const int2* __restrict__ col2, const float* __restrict__ dinv,
    const float* __restrict__ bias, uint32* __restrict__ Rout, int N, int NBH) {
  const int slice = (int)blockIdx.x >= NBH ? 1 : 0;
  const int nb = blockIdx.x - slice * NBH;
  const int lane = threadIdx.x & 63;
  const int widx = threadIdx.x >> 6;
  const int fl = lane & 15;   // u32 index within half row (feats 32*slice+2fl..)
  const int qtr = lane >> 4;  // edge slot

  int n = nb * 4 + widx;
  n = __builtin_amdgcn_readfirstlane(n);
  if (n >= N) return;

  int e0 = rowptr[n];
  int m = rowptr[n + 1] - e0;
  const int2* ec = col2 + e0;
  float di = dinv[n];
  const uint32* Hs = H32 + slice * 16 + fl;

  float acc0 = 0.f, acc1 = 0.f;
  const int nq = (m + 3) >> 2;
  for (int it = 0; it < nq; ++it) {
    int er = it * 4 + qtr;
    bool v = er < m;
    int2 c = ec[v ? er : 0];
    float w = v ? __int_as_float(c.y) : 0.f;
    uint32 u = Hs[(size_t)c.x * 32];
    acc0 = fmaf(w, bf2f_lo(u), acc0);
    acc1 = fmaf(w, bf2f_hi(u), acc1);
  }
  acc0 += __shfl_xor(acc0, 16, 64);
  acc1 += __shfl_xor(acc1, 16, 64);
  acc0 += __shfl_xor(acc0, 32, 64);
  acc1 += __shfl_xor(acc1, 32, 64);

  // self loop
  uint32 su = Hs[(size_t)n * 32];
  float d2 = di * di;
  acc0 = fmaf(d2, bf2f_lo(su), acc0);
  acc1 = fmaf(d2, bf2f_hi(su), acc1);

  float2 bv = ((const float2*)bias)[slice * 16 + fl];
  float r0 = fmaxf(acc0 + bv.x, 0.f);
  float r1 = fmaxf(acc1 + bv.y, 0.f);
  if (qtr == 0) {
    Rout[(size_t)n * 32 + slice * 16 + fl] =
        (uint32)f2bf(r0) | ((uint32)f2bf(r1) << 16);
  }
}

// transform: Hout = R @ W (64x64), bf16 rows in/out, streaming.
__global__ __launch_bounds__(256, 4) void transform_kernel(
    const uint32* __restrict__ R, const float* __restrict__ W,
    uint32* __restrict__ Hout, int N) {
  __shared__ float XsT[64][68];
  __shared__ float Ws[64 * 64];
  const int tid = threadIdx.x;
  const int n0 = blockIdx.x * 64;
  const int tn = (tid >> 4) * 4;
  const int tf = (tid & 15) * 4;
  {
    const float4* Wg = (const float4*)W;
    float4* Wl = (float4*)Ws;
#pragma unroll
    for (int j = 0; j < 4; ++j) Wl[tid + j * 256] = Wg[tid + j * 256];
  }
#pragma unroll
  for (int it = 0; it < 2; ++it) {
    int sb = it * 256 + tid;  // 0..511 = 64 nodes x 8 uint4
    int n = sb >> 3;
    int q = sb & 7;  // uint4 index within row (feats q*8..q*8+7)
    uint4 v = make_uint4(0, 0, 0, 0);
    if (n0 + n < N) v = *(const uint4*)(R + (size_t)(n0 + n) * 32 + q * 4);
    XsT[q * 8 + 0][n] = bf2f_lo(v.x);
    XsT[q * 8 + 1][n] = bf2f_hi(v.x);
    XsT[q * 8 + 2][n] = bf2f_lo(v.y);
    XsT[q * 8 + 3][n] = bf2f_hi(v.y);
    XsT[q * 8 + 4][n] = bf2f_lo(v.z);
    XsT[q * 8 + 5][n] = bf2f_hi(v.z);
    XsT[q * 8 + 6][n] = bf2f_lo(v.w);
    XsT[q * 8 + 7][n] = bf2f_hi(v.w);
  }
  __syncthreads();
  float acc[4][4];
#pragma unroll
  for (int i = 0; i < 4; ++i)
#pragma unroll
    for (int j = 0; j < 4; ++j) acc[i][j] = 0.f;
#pragma unroll 8
  for (int k = 0; k < 64; ++k) {
    float4 xv = *(const float4*)(&XsT[k][tn]);
    float4 wv = *(const float4*)(&Ws[k * 64 + tf]);
    acc[0][0] = fmaf(xv.x, wv.x, acc[0][0]);
    acc[0][1] = fmaf(xv.x, wv.y, acc[0][1]);
    acc[0][2] = fmaf(xv.x, wv.z, acc[0][2]);
    acc[0][3] = fmaf(xv.x, wv.w, acc[0][3]);
    acc[1][0] = fmaf(xv.y, wv.x, acc[1][0]);
    acc[1][1] = fmaf(xv.y, wv.y, acc[1][1]);
    acc[1][2] = fmaf(xv.y, wv.z, acc[1][2]);
    acc[1][3] = fmaf(xv.y, wv.w, acc[1][3]);
    acc[2][0] = fmaf(xv.z, wv.x, acc[2][0]);
    acc[2][1] = fmaf(xv.z, wv.y, acc[2][1]);
    acc[2][2] = fmaf(xv.z, wv.z, acc[2][2]);
    acc[2][3] = fmaf(xv.z, wv.w, acc[2][3]);
    acc[3][0] = fmaf(xv.w, wv.x, acc[3][0]);
    acc[3][1] = fmaf(xv.w, wv.y, acc[3][1]);
    acc[3][2] = fmaf(xv.w, wv.z, acc[3][2]);
    acc[3][3] = fmaf(xv.w, wv.w, acc[3][3]);
  }
#pragma unroll
  for (int i = 0; i < 4; ++i) {
    int n = n0 + tn + i;
    if (n < N) {
      uint32 a = (uint32)f2bf(acc[i][0]) | ((uint32)f2bf(acc[i][1]) << 16);
      uint32 b = (uint32)f2bf(acc[i][2]) | ((uint32)f2bf(acc[i][3]) << 16);
      *(uint2*)(Hout + (size_t)n * 32 + tf / 2) = make_uint2(a, b);
    }
  }
}

// ---------------- launcher ----------------

extern "C" void kernel_launch(void* const* d_in, const int* in_sizes, int n_in,
                              void* d_out, int out_size, void* d_ws, size_t ws_size,
                              hipStream_t stream) {
  const float* x  = (const float*)d_in[0];
  const int*   ei = (const int*)d_in[1];
  const float* W1 = (const float*)d_in[2];
  const float* b1 = (const float*)d_in[3];
  const float* W2 = (const float*)d_in[4];
  const float* b2 = (const float*)d_in[5];
  const float* W3 = (const float*)d_in[6];
  const float* b3 = (const float*)d_in[7];
  const float* Wl = (const float*)d_in[8];
  const float* bl = (const float*)d_in[9];
  float* out = (float*)d_out;

  const int N = in_sizes[0] / NF;  // 100000
  const int E = in_sizes[1] / 2;   // 1600000

  char* w = (char*)d_ws;
  size_t off = 0;
  auto alloc = [&](size_t bytes) {
    void* p = w + off;
    off += bytes;
    off = (off + 15) & ~(size_t)15;
    return p;
  };
  int*    cnt    = (int*)alloc((size_t)N * 4);
  int*    cnt2   = (int*)alloc((size_t)N * 4);
  int*    rowptr = (int*)alloc((size_t)(N + 1) * 4);
  int*    part   = (int*)alloc(256 * 4);
  float*  dinv   = (float*)alloc((size_t)N * 4);
  int2*   col2   = (int2*)alloc((size_t)E * 8);
  uint32* hA     = (uint32*)alloc((size_t)N * 32 * 4);  // bf16 x2 packed rows
  uint32* hB     = (uint32*)alloc((size_t)N * 32 * 4);

  const int NB = (N + 1023) / 1024;        // 98 (<=128 required by scanp)
  const int RW4 = (N + 3) / 4;             // 25000-node dst window (P=4)
  const int NCHUNK = (E / 4 + 255) / 256;  // edge-quad chunks
  const int G1 = ((((N + 63) / 64) + 3) / 4) * 4;  // gemm blocks (mult of 4)
  const int NBH = (N + 3) / 4;             // node blocks (4 waves each)

  hipMemsetAsync(cnt, 0, (size_t)N * 4, stream);
  hipLaunchKernelGGL(gemm1_count_kernel, dim3(G1 + 4 * NCHUNK), dim3(256), 0, stream,
                     x, W1, hA, N, ei, E, cnt, RW4, G1);
  hipLaunchKernelGGL(partial_kernel, dim3(NB), dim3(256), 0, stream, cnt, N, part);
  hipLaunchKernelGGL(scanp_kernel, dim3(1), dim3(128), 0, stream, part, NB, rowptr + N);
  hipLaunchKernelGGL(rowptr_kernel, dim3(NB), dim3(256), 0, stream,
                     cnt, part, rowptr, cnt2, dinv, N);
  hipLaunchKernelGGL(fill_kernel, dim3(4 * NCHUNK), dim3(256), 0, stream,
                     ei, E, cnt2, dinv, col2, RW4);

  // layer 1: full-row prop (hA -> hB, fused W2 transform)
  hipLaunchKernelGGL(prop_fused_kernel<0>, dim3(NBH), dim3(256), 0, stream,
                     hA, rowptr, col2, dinv, b1, W2, (const float*)nullptr, (void*)hB, N);
  // layer 2 (A/B): sliced half-row aggregation (hB -> hA), then W3 transform
  hipLaunchKernelGGL(agg_half_kernel, dim3(2 * NBH), dim3(256), 0, stream,
                     hB, rowptr, col2, dinv, b2, hA, N, NBH);
  hipLaunchKernelGGL(transform_kernel, dim3((N + 63) / 64), dim3(256), 0, stream,
                     hA, W3, hB, N);
  // layer 3: full-row prop + final linear/log_softmax (hB -> out)
  hipLaunchKernelGGL(prop_fused_kernel<1>, dim3(NBH), dim3(256), 0, stream,
                     hB, rowptr, col2, dinv, b3, Wl, bl, (void*)out, N);
}

// Round 13
// 420.703 us; speedup vs baseline: 1.1122x; 1.1122x over previous
//
#include <hip/hip_runtime.h>
#include <cstdint>
#include <cstddef>

#define NF 128
#define NH 64

typedef unsigned int uint32;
typedef short bf16x8 __attribute__((ext_vector_type(8)));
typedef float f32x4 __attribute__((ext_vector_type(4)));

// bf16 helpers (RNE pack, cheap unpack)
__device__ inline unsigned short f2bf(float f) {
  unsigned int u = __float_as_uint(f);
  return (unsigned short)((u + 0x7FFF + ((u >> 16) & 1)) >> 16);
}
__device__ inline float bf2f_lo(uint32 u) { return __uint_as_float(u << 16); }
__device__ inline float bf2f_hi(uint32 u) { return __uint_as_float(u & 0xFFFF0000u); }

// ---------------- fused gemm1 (MFMA) + count ----------------

// Blocks [0,G1): H = X @ W1 (f32 in, bf16-packed out) via mfma_f32_16x16x32_bf16.
// Blocks [G1,..): dst-windowed degree count, P=2 windows (pass = local&1;
// cnt window 200KB, L2-local).
__global__ __launch_bounds__(256) void gemm1_count_kernel(
    const float* __restrict__ X, const float* __restrict__ W,
    uint32* __restrict__ Hb, int N,
    const int* __restrict__ ei, int E, int* __restrict__ cnt, int RW, int G1) {
  if ((int)blockIdx.x >= G1) {
    int b = blockIdx.x - G1;
    int pass = b & 1;
    int i = (b >> 1) * 256 + threadIdx.x;
    if (i * 4 >= E) return;
    int4 d = ((const int4*)(ei + E))[i];
    int lo = pass * RW, hi = lo + RW;
    if (d.x >= lo && d.x < hi) atomicAdd(&cnt[d.x], 1);
    if (d.y >= lo && d.y < hi) atomicAdd(&cnt[d.y], 1);
    if (d.z >= lo && d.z < hi) atomicAdd(&cnt[d.z], 1);
    if (d.w >= lo && d.w < hi) atomicAdd(&cnt[d.w], 1);
    return;
  }

  // gemm1 (MFMA): wave = 16 nodes
  const int lane = threadIdx.x & 63;
  const int wv = threadIdx.x >> 6;
  const int m = lane & 15;
  const int g = lane >> 4;
  const int base = blockIdx.x * 64 + wv * 16;
  int row = base + m;
  int rowc = row < N ? row : N - 1;
  const float* xp = X + (size_t)rowc * 128 + g * 8;

  f32x4 acc[4];
#pragma unroll
  for (int nt = 0; nt < 4; ++nt) acc[nt] = (f32x4){0.f, 0.f, 0.f, 0.f};

#pragma unroll
  for (int kk = 0; kk < 4; ++kk) {
    float4 alo = *(const float4*)(xp + kk * 32);
    float4 ahi = *(const float4*)(xp + kk * 32 + 4);
    bf16x8 a;
    a[0] = (short)f2bf(alo.x); a[1] = (short)f2bf(alo.y);
    a[2] = (short)f2bf(alo.z); a[3] = (short)f2bf(alo.w);
    a[4] = (short)f2bf(ahi.x); a[5] = (short)f2bf(ahi.y);
    a[6] = (short)f2bf(ahi.z); a[7] = (short)f2bf(ahi.w);
    const float* wp = W + (size_t)(kk * 32 + g * 8) * 64 + m;
#pragma unroll
    for (int nt = 0; nt < 4; ++nt) {
      bf16x8 b;
#pragma unroll
      for (int i = 0; i < 8; ++i)
        b[i] = (short)f2bf(wp[(size_t)i * 64 + nt * 16]);
      acc[nt] = __builtin_amdgcn_mfma_f32_16x16x32_bf16(a, b, acc[nt], 0, 0, 0);
    }
  }
  unsigned short* Hs = (unsigned short*)Hb;
#pragma unroll
  for (int j = 0; j < 4; ++j) {
    int n = base + g * 4 + j;
    if (n < N) {
#pragma unroll
      for (int nt = 0; nt < 4; ++nt)
        Hs[(size_t)n * 64 + nt * 16 + m] = f2bf(acc[nt][j]);
    }
  }
}

// per-1024-element block sums
__global__ __launch_bounds__(256) void partial_kernel(const int* __restrict__ cnt, int N,
                                                      int* __restrict__ part) {
  __shared__ int sd[256];
  int t = threadIdx.x;
  int idx = blockIdx.x * 1024 + t * 4;
  int s = 0;
#pragma unroll
  for (int j = 0; j < 4; ++j)
    if (idx + j < N) s += cnt[idx + j];
  sd[t] = s;
  __syncthreads();
  for (int off = 128; off > 0; off >>= 1) {
    if (t < off) sd[t] += sd[t + off];
    __syncthreads();
  }
  if (t == 0) part[blockIdx.x] = sd[0];
}

// exclusive-scan the block partials (NB <= 128), write total to rowptr[N]
__global__ __launch_bounds__(128) void scanp_kernel(int* __restrict__ part, int NB,
                                                    int* __restrict__ rowptrN) {
  __shared__ int s[128];
  int t = threadIdx.x;
  int v = (t < NB) ? part[t] : 0;
  s[t] = v;
  __syncthreads();
  for (int off = 1; off < 128; off <<= 1) {
    int add = (t >= off) ? s[t - off] : 0;
    __syncthreads();
    s[t] += add;
    __syncthreads();
  }
  if (t < NB) part[t] = s[t] - v;  // exclusive
  if (t == 0) rowptrN[0] = s[127];
}

// rowptr (exclusive scan of cnt) + cnt2 (running cursor copy) + dinv
__global__ __launch_bounds__(256) void rowptr_kernel(const int* __restrict__ cnt,
                                                     const int* __restrict__ part,
                                                     int* __restrict__ rowptr,
                                                     int* __restrict__ cnt2,
                                                     float* __restrict__ dinv, int N) {
  __shared__ int s[256];
  int t = threadIdx.x;
  int idx = blockIdx.x * 1024 + t * 4;
  int c[4];
  int ts = 0;
#pragma unroll
  for (int j = 0; j < 4; ++j) {
    c[j] = (idx + j < N) ? cnt[idx + j] : 0;
    ts += c[j];
  }
  s[t] = ts;
  __syncthreads();
  for (int off = 1; off < 256; off <<= 1) {
    int add = (t >= off) ? s[t - off] : 0;
    __syncthreads();
    s[t] += add;
    __syncthreads();
  }
  int run = s[t] - ts + part[blockIdx.x];
#pragma unroll
  for (int j = 0; j < 4; ++j) {
    if (idx + j < N) {
      rowptr[idx + j] = run;
      cnt2[idx + j] = run;
      dinv[idx + j] = rsqrtf((float)(c[j] + 1));
    }
    run += c[j];
  }
}

// dst-windowed CSR scatter (src, weight), P=4 windows: col2 window 3.2MB,
// assembles in L2 before writeback.
__global__ __launch_bounds__(256) void fill_kernel(const int* __restrict__ ei, int E,
                                                   int* __restrict__ cnt2,
                                                   const float* __restrict__ dinv,
                                                   int2* __restrict__ col2, int RW) {
  int pass = blockIdx.x & 3;
  int i = (blockIdx.x >> 2) * 256 + threadIdx.x;
  if (i * 4 >= E) return;
  int4 sv = ((const int4*)ei)[i];
  int4 dv = ((const int4*)(ei + E))[i];
  int lo = pass * RW, hi = lo + RW;
  int ss[4] = {sv.x, sv.y, sv.z, sv.w};
  int dd[4] = {dv.x, dv.y, dv.z, dv.w};
#pragma unroll
  for (int j = 0; j < 4; ++j) {
    int d = dd[j];
    if (d < lo || d >= hi) continue;
    int s = ss[j];
    float w = dinv[s] * dinv[d];
    int pos = atomicAdd(&cnt2[d], 1);
    col2[pos] = make_int2(s, __float_as_int(w));
  }
}

// ---------------- prop kernel (R6 winner) ----------------

// Fused CSR aggregate over bf16 H (wave = node; lane = feature-PAIR; two
// 32-lane halves process even/odd edges -> 2 edges per gather instruction)
// + bias + relu + next-layer 64x64 linear via wave-local LDS exchange.
// FINAL=1: 64->2 linear + log_softmax instead.
template <int FINAL>
__global__ __launch_bounds__(256) void prop_fused_kernel(
    const uint32* __restrict__ H32, const int* __restrict__ rowptr,
    const int2* __restrict__ col2, const float* __restrict__ dinv,
    const float* __restrict__ bias, const float* __restrict__ Wn,
    const float* __restrict__ blin, void* __restrict__ outv, int N) {
  __shared__ float Ws[FINAL ? 4 : 64 * 64];
  __shared__ float rbuf[FINAL ? 1 : 4][64];
  const int lane = threadIdx.x & 63;
  const int widx = threadIdx.x >> 6;
  const int fl = lane & 31;
  const int half = lane >> 5;

  if (!FINAL) {
    const float4* Wg = (const float4*)Wn;
    float4* Wl = (float4*)Ws;
    for (int i = threadIdx.x; i < 1024; i += 256) Wl[i] = Wg[i];
    __syncthreads();
  }

  int n = blockIdx.x * 4 + widx;
  n = __builtin_amdgcn_readfirstlane(n);
  if (n >= N) return;

  int e0 = rowptr[n];
  int e1 = rowptr[n + 1];
  float di = dinv[n];
  const int2* ec = col2 + e0;
  const int m = e1 - e0;

  float acc0 = 0.f, acc1 = 0.f;
  if (half == 0) {
    uint32 u = H32[(size_t)n * 32 + fl];
    float w = di * di;
    acc0 = bf2f_lo(u) * w;
    acc1 = bf2f_hi(u) * w;
  }

  const int npair = m >> 1;
  const int nfull = npair >> 3;
  for (int b = 0; b < nfull; ++b) {
    int s[8];
    float wv[8];
#pragma unroll
    for (int j = 0; j < 8; ++j) {
      int2 c = ec[2 * (b * 8 + j) + half];
      s[j] = c.x;
      wv[j] = __int_as_float(c.y);
    }
    uint32 u[8];
#pragma unroll
    for (int j = 0; j < 8; ++j) u[j] = H32[(size_t)s[j] * 32 + fl];
#pragma unroll
    for (int j = 0; j < 8; ++j) {
      acc0 = fmaf(wv[j], bf2f_lo(u[j]), acc0);
      acc1 = fmaf(wv[j], bf2f_hi(u[j]), acc1);
    }
  }
  for (int t = nfull * 8; t < npair; ++t) {
    int2 c = ec[2 * t + half];
    uint32 u = H32[(size_t)c.x * 32 + fl];
    float w = __int_as_float(c.y);
    acc0 = fmaf(w, bf2f_lo(u), acc0);
    acc1 = fmaf(w, bf2f_hi(u), acc1);
  }
  if ((m & 1) && half == 0) {
    int2 c = ec[m - 1];
    uint32 u = H32[(size_t)c.x * 32 + fl];
    float w = __int_as_float(c.y);
    acc0 = fmaf(w, bf2f_lo(u), acc0);
    acc1 = fmaf(w, bf2f_hi(u), acc1);
  }
  acc0 += __shfl_xor(acc0, 32, 64);
  acc1 += __shfl_xor(acc1, 32, 64);

  float2 bv = ((const float2*)bias)[fl];
  float r0 = acc0 + bv.x;
  float r1 = acc1 + bv.y;
  r0 = r0 > 0.f ? r0 : 0.f;
  r1 = r1 > 0.f ? r1 : 0.f;

  if (FINAL) {
    float t0 = 0.f, t1 = 0.f;
    if (half == 0) {
      t0 = r0 * Wn[4 * fl + 0] + r1 * Wn[4 * fl + 2];
      t1 = r0 * Wn[4 * fl + 1] + r1 * Wn[4 * fl + 3];
    }
#pragma unroll
    for (int off = 32; off > 0; off >>= 1) {
      t0 += __shfl_xor(t0, off, 64);
      t1 += __shfl_xor(t1, off, 64);
    }
    if (lane == 0) {
      float* out = (float*)outv;
      float l0 = t0 + blin[0];
      float l1 = t1 + blin[1];
      float mx = fmaxf(l0, l1);
      float lz = mx + logf(expf(l0 - mx) + expf(l1 - mx));
      out[(size_t)n * 2 + 0] = l0 - lz;
      out[(size_t)n * 2 + 1] = l1 - lz;
    }
  } else {
    if (half == 0) *(float2*)(&rbuf[widx][2 * fl]) = make_float2(r0, r1);
    __builtin_amdgcn_wave_barrier();
    float o = 0.f;
#pragma unroll
    for (int q = 0; q < 16; ++q) {
      float4 rv = *(const float4*)(&rbuf[widx][4 * q]);
      o = fmaf(rv.x, Ws[(4 * q + 0) * 64 + lane], o);
      o = fmaf(rv.y, Ws[(4 * q + 1) * 64 + lane], o);
      o = fmaf(rv.z, Ws[(4 * q + 2) * 64 + lane], o);
      o = fmaf(rv.w, Ws[(4 * q + 3) * 64 + lane], o);
    }
    ((unsigned short*)outv)[(size_t)n * 64 + lane] = f2bf(o);
  }
}

// ---------------- launcher ----------------

extern "C" void kernel_launch(void* const* d_in, const int* in_sizes, int n_in,
                              void* d_out, int out_size, void* d_ws, size_t ws_size,
                              hipStream_t stream) {
  const float* x  = (const float*)d_in[0];
  const int*   ei = (const int*)d_in[1];
  const float* W1 = (const float*)d_in[2];
  const float* b1 = (const float*)d_in[3];
  const float* W2 = (const float*)d_in[4];
  const float* b2 = (const float*)d_in[5];
  const float* W3 = (const float*)d_in[6];
  const float* b3 = (const float*)d_in[7];
  const float* Wl = (const float*)d_in[8];
  const float* bl = (const float*)d_in[9];
  float* out = (float*)d_out;

  const int N = in_sizes[0] / NF;  // 100000
  const int E = in_sizes[1] / 2;   // 1600000

  char* w = (char*)d_ws;
  size_t off = 0;
  auto alloc = [&](size_t bytes) {
    void* p = w + off;
    off += bytes;
    off = (off + 15) & ~(size_t)15;
    return p;
  };
  int*    cnt    = (int*)alloc((size_t)N * 4);
  int*    cnt2   = (int*)alloc((size_t)N * 4);
  int*    rowptr = (int*)alloc((size_t)(N + 1) * 4);
  int*    part   = (int*)alloc(256 * 4);
  float*  dinv   = (float*)alloc((size_t)N * 4);
  int2*   col2   = (int2*)alloc((size_t)E * 8);
  uint32* hA     = (uint32*)alloc((size_t)N * 32 * 4);  // bf16 x2 packed rows
  uint32* hB     = (uint32*)alloc((size_t)N * 32 * 4);

  const int NB = (N + 1023) / 1024;        // 98 (<=128 required by scanp)
  const int RW2 = (N + 1) / 2;             // 50000-node dst window (count, P=2)
  const int RW4 = (N + 3) / 4;             // 25000-node dst window (fill, P=4)
  const int NCHUNK = (E / 4 + 255) / 256;  // edge-quad chunks
  const int G1 = ((((N + 63) / 64) + 1) / 2) * 2;  // gemm blocks (mult of 2)
  const int NBH = (N + 3) / 4;             // prop blocks (4 waves each)

  hipMemsetAsync(cnt, 0, (size_t)N * 4, stream);
  hipLaunchKernelGGL(gemm1_count_kernel, dim3(G1 + 2 * NCHUNK), dim3(256), 0, stream,
                     x, W1, hA, N, ei, E, cnt, RW2, G1);
  hipLaunchKernelGGL(partial_kernel, dim3(NB), dim3(256), 0, stream, cnt, N, part);
  hipLaunchKernelGGL(scanp_kernel, dim3(1), dim3(128), 0, stream, part, NB, rowptr + N);
  hipLaunchKernelGGL(rowptr_kernel, dim3(NB), dim3(256), 0, stream,
                     cnt, part, rowptr, cnt2, dinv, N);
  hipLaunchKernelGGL(fill_kernel, dim3(4 * NCHUNK), dim3(256), 0, stream,
                     ei, E, cnt2, dinv, col2, RW4);

  hipLaunchKernelGGL(prop_fused_kernel<0>, dim3(NBH), dim3(256), 0, stream,
                     hA, rowptr, col2, dinv, b1, W2, (const float*)nullptr, (void*)hB, N);
  hipLaunchKernelGGL(prop_fused_kernel<0>, dim3(NBH), dim3(256), 0, stream,
                     hB, rowptr, col2, dinv, b2, W3, (const float*)nullptr, (void*)hA, N);
  hipLaunchKernelGGL(prop_fused_kernel<1>, dim3(NBH), dim3(256), 0, stream,
                     hA, rowptr, col2, dinv, b3, Wl, bl, (void*)out, N);
}

// Round 14
// 418.618 us; speedup vs baseline: 1.1178x; 1.0050x over previous
//
#include <hip/hip_runtime.h>
#include <cstdint>
#include <cstddef>

#define NF 128
#define NH 64
#define TSH 14  // src-tile = src >> 14 (16384 nodes = 2MB bf16 slice per tile)
#define NT8 8   // tile slots per node (max tile index for N=100000 is 6)

typedef unsigned int uint32;
typedef short bf16x8 __attribute__((ext_vector_type(8)));
typedef float f32x4 __attribute__((ext_vector_type(4)));

// bf16 helpers (RNE pack, cheap unpack)
__device__ inline unsigned short f2bf(float f) {
  unsigned int u = __float_as_uint(f);
  return (unsigned short)((u + 0x7FFF + ((u >> 16) & 1)) >> 16);
}
__device__ inline float bf2f_lo(uint32 u) { return __uint_as_float(u << 16); }
__device__ inline float bf2f_hi(uint32 u) { return __uint_as_float(u & 0xFFFF0000u); }

// ---------------- fused gemm1 (MFMA) + count ----------------

// Blocks [0,G1): H = X @ W1 (f32 in, bf16-packed out) via mfma_f32_16x16x32_bf16.
// Blocks [G1,..): per-(dst, src-tile) degree count, P=2 dst windows.
__global__ __launch_bounds__(256) void gemm1_count_kernel(
    const float* __restrict__ X, const float* __restrict__ W,
    uint32* __restrict__ Hb, int N,
    const int* __restrict__ ei, int E, int* __restrict__ cnt, int RW, int G1) {
  if ((int)blockIdx.x >= G1) {
    int b = blockIdx.x - G1;
    int pass = b & 1;
    int i = (b >> 1) * 256 + threadIdx.x;
    if (i * 4 >= E) return;
    int4 s4 = ((const int4*)ei)[i];
    int4 d4 = ((const int4*)(ei + E))[i];
    int lo = pass * RW, hi = lo + RW;
    if (d4.x >= lo && d4.x < hi) atomicAdd(&cnt[d4.x * NT8 + (s4.x >> TSH)], 1);
    if (d4.y >= lo && d4.y < hi) atomicAdd(&cnt[d4.y * NT8 + (s4.y >> TSH)], 1);
    if (d4.z >= lo && d4.z < hi) atomicAdd(&cnt[d4.z * NT8 + (s4.z >> TSH)], 1);
    if (d4.w >= lo && d4.w < hi) atomicAdd(&cnt[d4.w * NT8 + (s4.w >> TSH)], 1);
    return;
  }

  // gemm1 (MFMA): wave = 16 nodes
  const int lane = threadIdx.x & 63;
  const int wv = threadIdx.x >> 6;
  const int m = lane & 15;
  const int g = lane >> 4;
  const int base = blockIdx.x * 64 + wv * 16;
  int row = base + m;
  int rowc = row < N ? row : N - 1;
  const float* xp = X + (size_t)rowc * 128 + g * 8;

  f32x4 acc[4];
#pragma unroll
  for (int nt = 0; nt < 4; ++nt) acc[nt] = (f32x4){0.f, 0.f, 0.f, 0.f};

#pragma unroll
  for (int kk = 0; kk < 4; ++kk) {
    float4 alo = *(const float4*)(xp + kk * 32);
    float4 ahi = *(const float4*)(xp + kk * 32 + 4);
    bf16x8 a;
    a[0] = (short)f2bf(alo.x); a[1] = (short)f2bf(alo.y);
    a[2] = (short)f2bf(alo.z); a[3] = (short)f2bf(alo.w);
    a[4] = (short)f2bf(ahi.x); a[5] = (short)f2bf(ahi.y);
    a[6] = (short)f2bf(ahi.z); a[7] = (short)f2bf(ahi.w);
    const float* wp = W + (size_t)(kk * 32 + g * 8) * 64 + m;
#pragma unroll
    for (int nt = 0; nt < 4; ++nt) {
      bf16x8 b;
#pragma unroll
      for (int i = 0; i < 8; ++i)
        b[i] = (short)f2bf(wp[(size_t)i * 64 + nt * 16]);
      acc[nt] = __builtin_amdgcn_mfma_f32_16x16x32_bf16(a, b, acc[nt], 0, 0, 0);
    }
  }
  unsigned short* Hs = (unsigned short*)Hb;
#pragma unroll
  for (int j = 0; j < 4; ++j) {
    int n = base + g * 4 + j;
    if (n < N) {
#pragma unroll
      for (int nt = 0; nt < 4; ++nt)
        Hs[(size_t)n * 64 + nt * 16 + m] = f2bf(acc[nt][j]);
    }
  }
}

// per-1024-node block sums over the [N][8] count grid
__global__ __launch_bounds__(256) void partial_kernel(const int* __restrict__ cnt, int N,
                                                      int* __restrict__ part) {
  __shared__ int sd[256];
  int t = threadIdx.x;
  int idx = blockIdx.x * 1024 + t * 4;
  int s = 0;
#pragma unroll
  for (int j = 0; j < 4; ++j) {
    if (idx + j < N) {
      int4 a = ((const int4*)cnt)[(idx + j) * 2];
      int4 b = ((const int4*)cnt)[(idx + j) * 2 + 1];
      s += a.x + a.y + a.z + a.w + b.x + b.y + b.z + b.w;
    }
  }
  sd[t] = s;
  __syncthreads();
  for (int off = 128; off > 0; off >>= 1) {
    if (t < off) sd[t] += sd[t + off];
    __syncthreads();
  }
  if (t == 0) part[blockIdx.x] = sd[0];
}

// exclusive-scan the block partials (NB <= 128), write total to rowptr[N]
__global__ __launch_bounds__(128) void scanp_kernel(int* __restrict__ part, int NB,
                                                    int* __restrict__ rowptrN) {
  __shared__ int s[128];
  int t = threadIdx.x;
  int v = (t < NB) ? part[t] : 0;
  s[t] = v;
  __syncthreads();
  for (int off = 1; off < 128; off <<= 1) {
    int add = (t >= off) ? s[t - off] : 0;
    __syncthreads();
    s[t] += add;
    __syncthreads();
  }
  if (t < NB) part[t] = s[t] - v;  // exclusive
  if (t == 0) rowptrN[0] = s[127];
}

// rowptr (exclusive scan of per-node totals) + per-(node,tile) cursors + dinv
__global__ __launch_bounds__(256) void rowptr_kernel(const int* __restrict__ cnt,
                                                     const int* __restrict__ part,
                                                     int* __restrict__ rowptr,
                                                     int* __restrict__ cur,
                                                     float* __restrict__ dinv, int N) {
  __shared__ int s[256];
  int t = threadIdx.x;
  int idx = blockIdx.x * 1024 + t * 4;
  int cc[4][8];
  int c[4];
  int ts = 0;
#pragma unroll
  for (int j = 0; j < 4; ++j) {
    int sum = 0;
    if (idx + j < N) {
      int4 a = ((const int4*)cnt)[(idx + j) * 2];
      int4 b = ((const int4*)cnt)[(idx + j) * 2 + 1];
      cc[j][0] = a.x; cc[j][1] = a.y; cc[j][2] = a.z; cc[j][3] = a.w;
      cc[j][4] = b.x; cc[j][5] = b.y; cc[j][6] = b.z; cc[j][7] = b.w;
      sum = a.x + a.y + a.z + a.w + b.x + b.y + b.z + b.w;
    } else {
#pragma unroll
      for (int q = 0; q < 8; ++q) cc[j][q] = 0;
    }
    c[j] = sum;
    ts += sum;
  }
  s[t] = ts;
  __syncthreads();
  for (int off = 1; off < 256; off <<= 1) {
    int add = (t >= off) ? s[t - off] : 0;
    __syncthreads();
    s[t] += add;
    __syncthreads();
  }
  int run = s[t] - ts + part[blockIdx.x];
#pragma unroll
  for (int j = 0; j < 4; ++j) {
    if (idx + j < N) {
      rowptr[idx + j] = run;
      int cum = run;
#pragma unroll
      for (int q = 0; q < 8; ++q) {
        cur[(idx + j) * NT8 + q] = cum;
        cum += cc[j][q];
      }
      dinv[idx + j] = rsqrtf((float)(c[j] + 1));
    }
    run += c[j];
  }
}

// dst-windowed CSR scatter (src, weight), P=4 windows; edges land src-tile-
// sorted within each row via per-(dst,tile) cursors.
__global__ __launch_bounds__(256) void fill_kernel(const int* __restrict__ ei, int E,
                                                   int* __restrict__ cur,
                                                   const float* __restrict__ dinv,
                                                   int2* __restrict__ col2, int RW) {
  int pass = blockIdx.x & 3;
  int i = (blockIdx.x >> 2) * 256 + threadIdx.x;
  if (i * 4 >= E) return;
  int4 sv = ((const int4*)ei)[i];
  int4 dv = ((const int4*)(ei + E))[i];
  int lo = pass * RW, hi = lo + RW;
  int ss[4] = {sv.x, sv.y, sv.z, sv.w};
  int dd[4] = {dv.x, dv.y, dv.z, dv.w};
#pragma unroll
  for (int j = 0; j < 4; ++j) {
    int d = dd[j];
    if (d < lo || d >= hi) continue;
    int s = ss[j];
    float w = dinv[s] * dinv[d];
    int pos = atomicAdd(&cur[d * NT8 + (s >> TSH)], 1);
    col2[pos] = make_int2(s, __float_as_int(w));
  }
}

// ---------------- prop kernel (R6 winner, UNCHANGED) ----------------

template <int FINAL>
__global__ __launch_bounds__(256) void prop_fused_kernel(
    const uint32* __restrict__ H32, const int* __restrict__ rowptr,
    const int2* __restrict__ col2, const float* __restrict__ dinv,
    const float* __restrict__ bias, const float* __restrict__ Wn,
    const float* __restrict__ blin, void* __restrict__ outv, int N) {
  __shared__ float Ws[FINAL ? 4 : 64 * 64];
  __shared__ float rbuf[FINAL ? 1 : 4][64];
  const int lane = threadIdx.x & 63;
  const int widx = threadIdx.x >> 6;
  const int fl = lane & 31;
  const int half = lane >> 5;

  if (!FINAL) {
    const float4* Wg = (const float4*)Wn;
    float4* Wl = (float4*)Ws;
    for (int i = threadIdx.x; i < 1024; i += 256) Wl[i] = Wg[i];
    __syncthreads();
  }

  int n = blockIdx.x * 4 + widx;
  n = __builtin_amdgcn_readfirstlane(n);
  if (n >= N) return;

  int e0 = rowptr[n];
  int e1 = rowptr[n + 1];
  float di = dinv[n];
  const int2* ec = col2 + e0;
  const int m = e1 - e0;

  float acc0 = 0.f, acc1 = 0.f;
  if (half == 0) {
    uint32 u = H32[(size_t)n * 32 + fl];
    float w = di * di;
    acc0 = bf2f_lo(u) * w;
    acc1 = bf2f_hi(u) * w;
  }

  const int npair = m >> 1;
  const int nfull = npair >> 3;
  for (int b = 0; b < nfull; ++b) {
    int s[8];
    float wv[8];
#pragma unroll
    for (int j = 0; j < 8; ++j) {
      int2 c = ec[2 * (b * 8 + j) + half];
      s[j] = c.x;
      wv[j] = __int_as_float(c.y);
    }
    uint32 u[8];
#pragma unroll
    for (int j = 0; j < 8; ++j) u[j] = H32[(size_t)s[j] * 32 + fl];
#pragma unroll
    for (int j = 0; j < 8; ++j) {
      acc0 = fmaf(wv[j], bf2f_lo(u[j]), acc0);
      acc1 = fmaf(wv[j], bf2f_hi(u[j]), acc1);
    }
  }
  for (int t = nfull * 8; t < npair; ++t) {
    int2 c = ec[2 * t + half];
    uint32 u = H32[(size_t)c.x * 32 + fl];
    float w = __int_as_float(c.y);
    acc0 = fmaf(w, bf2f_lo(u), acc0);
    acc1 = fmaf(w, bf2f_hi(u), acc1);
  }
  if ((m & 1) && half == 0) {
    int2 c = ec[m - 1];
    uint32 u = H32[(size_t)c.x * 32 + fl];
    float w = __int_as_float(c.y);
    acc0 = fmaf(w, bf2f_lo(u), acc0);
    acc1 = fmaf(w, bf2f_hi(u), acc1);
  }
  acc0 += __shfl_xor(acc0, 32, 64);
  acc1 += __shfl_xor(acc1, 32, 64);

  float2 bv = ((const float2*)bias)[fl];
  float r0 = acc0 + bv.x;
  float r1 = acc1 + bv.y;
  r0 = r0 > 0.f ? r0 : 0.f;
  r1 = r1 > 0.f ? r1 : 0.f;

  if (FINAL) {
    float t0 = 0.f, t1 = 0.f;
    if (half == 0) {
      t0 = r0 * Wn[4 * fl + 0] + r1 * Wn[4 * fl + 2];
      t1 = r0 * Wn[4 * fl + 1] + r1 * Wn[4 * fl + 3];
    }
#pragma unroll
    for (int off = 32; off > 0; off >>= 1) {
      t0 += __shfl_xor(t0, off, 64);
      t1 += __shfl_xor(t1, off, 64);
    }
    if (lane == 0) {
      float* out = (float*)outv;
      float l0 = t0 + blin[0];
      float l1 = t1 + blin[1];
      float mx = fmaxf(l0, l1);
      float lz = mx + logf(expf(l0 - mx) + expf(l1 - mx));
      out[(size_t)n * 2 + 0] = l0 - lz;
      out[(size_t)n * 2 + 1] = l1 - lz;
    }
  } else {
    if (half == 0) *(float2*)(&rbuf[widx][2 * fl]) = make_float2(r0, r1);
    __builtin_amdgcn_wave_barrier();
    float o = 0.f;
#pragma unroll
    for (int q = 0; q < 16; ++q) {
      float4 rv = *(const float4*)(&rbuf[widx][4 * q]);
      o = fmaf(rv.x, Ws[(4 * q + 0) * 64 + lane], o);
      o = fmaf(rv.y, Ws[(4 * q + 1) * 64 + lane], o);
      o = fmaf(rv.z, Ws[(4 * q + 2) * 64 + lane], o);
      o = fmaf(rv.w, Ws[(4 * q + 3) * 64 + lane], o);
    }
    ((unsigned short*)outv)[(size_t)n * 64 + lane] = f2bf(o);
  }
}

// ---------------- launcher ----------------

extern "C" void kernel_launch(void* const* d_in, const int* in_sizes, int n_in,
                              void* d_out, int out_size, void* d_ws, size_t ws_size,
                              hipStream_t stream) {
  const float* x  = (const float*)d_in[0];
  const int*   ei = (const int*)d_in[1];
  const float* W1 = (const float*)d_in[2];
  const float* b1 = (const float*)d_in[3];
  const float* W2 = (const float*)d_in[4];
  const float* b2 = (const float*)d_in[5];
  const float* W3 = (const float*)d_in[6];
  const float* b3 = (const float*)d_in[7];
  const float* Wl = (const float*)d_in[8];
  const float* bl = (const float*)d_in[9];
  float* out = (float*)d_out;

  const int N = in_sizes[0] / NF;  // 100000
  const int E = in_sizes[1] / 2;   // 1600000

  char* w = (char*)d_ws;
  size_t off = 0;
  auto alloc = [&](size_t bytes) {
    void* p = w + off;
    off += bytes;
    off = (off + 15) & ~(size_t)15;
    return p;
  };
  int*    cnt    = (int*)alloc((size_t)N * NT8 * 4);  // per-(node,tile) counts
  int*    cur    = (int*)alloc((size_t)N * NT8 * 4);  // fill cursors
  int*    rowptr = (int*)alloc((size_t)(N + 1) * 4);
  int*    part   = (int*)alloc(256 * 4);
  float*  dinv   = (float*)alloc((size_t)N * 4);
  int2*   col2   = (int2*)alloc((size_t)E * 8);
  uint32* hA     = (uint32*)alloc((size_t)N * 32 * 4);  // bf16 x2 packed rows
  uint32* hB     = (uint32*)alloc((size_t)N * 32 * 4);

  const int NB = (N + 1023) / 1024;        // 98 (<=128 required by scanp)
  const int RW2 = (N + 1) / 2;             // 50000-node dst window (count, P=2)
  const int RW4 = (N + 3) / 4;             // 25000-node dst window (fill, P=4)
  const int NCHUNK = (E / 4 + 255) / 256;  // edge-quad chunks
  const int G1 = ((((N + 63) / 64) + 1) / 2) * 2;  // gemm blocks (mult of 2)
  const int NBH = (N + 3) / 4;             // prop blocks (4 waves each)

  hipMemsetAsync(cnt, 0, (size_t)N * NT8 * 4, stream);
  hipLaunchKernelGGL(gemm1_count_kernel, dim3(G1 + 2 * NCHUNK), dim3(256), 0, stream,
                     x, W1, hA, N, ei, E, cnt, RW2, G1);
  hipLaunchKernelGGL(partial_kernel, dim3(NB), dim3(256), 0, stream, cnt, N, part);
  hipLaunchKernelGGL(scanp_kernel, dim3(1), dim3(128), 0, stream, part, NB, rowptr + N);
  hipLaunchKernelGGL(rowptr_kernel, dim3(NB), dim3(256), 0, stream,
                     cnt, part, rowptr, cur, dinv, N);
  hipLaunchKernelGGL(fill_kernel, dim3(4 * NCHUNK), dim3(256), 0, stream,
                     ei, E, cur, dinv, col2, RW4);

  hipLaunchKernelGGL(prop_fused_kernel<0>, dim3(NBH), dim3(256), 0, stream,
                     hA, rowptr, col2, dinv, b1, W2, (const float*)nullptr, (void*)hB, N);
  hipLaunchKernelGGL(prop_fused_kernel<0>, dim3(NBH), dim3(256), 0, stream,
                     hB, rowptr, col2, dinv, b2, W3, (const float*)nullptr, (void*)hA, N);
  hipLaunchKernelGGL(prop_fused_kernel<1>, dim3(NBH), dim3(256), 0, stream,
                     hA, rowptr, col2, dinv, b3, Wl, bl, (void*)out, N);
}